// Round 6
// baseline (666.223 us; speedup 1.0000x reference)
//
#include <hip/hip_runtime.h>
#include <hip/hip_bf16.h>

// B=64, D=1024, M=1024, DMODEL=1024, PRED_LEN=96
//   hp[b,i,f] = sum_c h[b,i,c]*pw[f,c] + pb[f]
//   P [b,i,f] = sum_m u[i,m]*lam[b,f,m]
//   diag[b,i] = sum_f hp[b,i,f]*P[b,i,f];  out[b,i,:] = diag[b,i] + bias[i]
//
// ONE fused kernel per (b, i-tile, f-tile): hp-tile GEMM (c-loop) reading h
// as f32 via reg-staging (global->reg->cvt->swizzled ds_write) and pw as bf16
// via global_load_lds; pack hp in regs; P-tile GEMM (m-loop) same with lam
// f32-side; in-register hadamard/rowsum -> 16 partial strips -> broadcast.
// Only u/pw (2 MB each) get pre-convert kernels.

#define D_    1024
#define BATCH 64
#define PRED  96

typedef __attribute__((ext_vector_type(8))) short  bf16x8;
typedef __attribute__((ext_vector_type(8))) ushort ushort8;
typedef __attribute__((ext_vector_type(4))) float  f32x4;
typedef __attribute__((ext_vector_type(4))) ushort us4;

__device__ __forceinline__ ushort f2bf(float f){
  union { __hip_bfloat16 b; ushort u; } cv;
  cv.b = __float2bfloat16(f);
  return cv.u;
}
__device__ __forceinline__ float bf2f(ushort v){
  union { ushort u; __hip_bfloat16 b; } cv;
  cv.u = v;
  return __bfloat162float(cv.b);
}

// bijective XCD swizzle (m204 form)
__device__ __forceinline__ int xcd_swz(int orig, int nwg){
  int q = nwg >> 3, r = nwg & 7;
  int x = orig & 7, o = orig >> 3;
  return (x < r ? x*(q+1) : r*(q+1) + (x-r)*q) + o;
}

// async global->LDS, 16B per lane; LDS dest = wave-uniform base + lane*16
__device__ __forceinline__ void gload16(const ushort* g, ushort* l){
  __builtin_amdgcn_global_load_lds(
      (const __attribute__((address_space(1))) void*)g,
      (__attribute__((address_space(3))) void*)l, 16, 0, 0);
}

// ------- f32 -> bf16 convert (for small u/pw only) -------
__global__ __launch_bounds__(256) void cvt_bf16(const float* __restrict__ in,
                                                ushort* __restrict__ out, int n4){
  int stride = (int)gridDim.x * 256;
  for (int i = (int)blockIdx.x*256 + (int)threadIdx.x; i < n4; i += stride){
    f32x4 a = __builtin_nontemporal_load((const f32x4*)in + i);
    us4 o;
    o.x = f2bf(a.x); o.y = f2bf(a.y); o.z = f2bf(a.z); o.w = f2bf(a.w);
    *(us4*)(out + (size_t)i*4) = o;
  }
}

// ---- staging building blocks (used by the pipelined core) ----
// bf16 side: 4 x global_load_lds (linear LDS dest, pre-swizzled source col)
#define ISSUE_BF(PAN, TOFF, SDST)                                               \
  _Pragma("unroll")                                                             \
  for (int q = 0; q < 4; ++q){                                                  \
    int _r0 = q*32 + wv*8;                                                      \
    gload16((PAN) + (TOFF) + (size_t)(_r0 + srow)*D_ + scol, (SDST) + _r0*64);  \
  }

// f32 side: 8 x global_load_dwordx4 into register set R (tile = 128x64 f32)
#define ISSUE_F32(PAN, TOFF, R)                                                 \
  _Pragma("unroll")                                                             \
  for (int j = 0; j < 4; ++j){                                                  \
    const float* _p = (PAN) + (TOFF) + (size_t)(j*32 + rrow)*D_ + rcol;         \
    R[2*j]   = *(const f32x4*)_p;                                               \
    R[2*j+1] = *(const f32x4*)(_p + 4);                                         \
  }

// cvt reg set -> bf16, swizzled ds_write_b128 (matches frag-read XOR layout)
#define DSW(R, SDST)                                                            \
  _Pragma("unroll")                                                             \
  for (int j = 0; j < 4; ++j){                                                  \
    ushort8 _w;                                                                 \
    _w[0]=f2bf(R[2*j][0]);   _w[1]=f2bf(R[2*j][1]);                             \
    _w[2]=f2bf(R[2*j][2]);   _w[3]=f2bf(R[2*j][3]);                             \
    _w[4]=f2bf(R[2*j+1][0]); _w[5]=f2bf(R[2*j+1][1]);                           \
    _w[6]=f2bf(R[2*j+1][2]); _w[7]=f2bf(R[2*j+1][3]);                           \
    *(ushort8*)((SDST) + (j*32 + rrow)*64 + rsw) = _w;                          \
  }

// One pipeline phase: compute tile T from buf CUR; stage tile T+2 (bf16 side
// direct to LDS, f32 side to regs RC); ds_write tile T+1 (RN) into buf CUR^1.
// 12 VMEM ops/tile -> vmcnt(12) keeps exactly one future tile in flight.
#define PHASE(CUR, RC, RN, T, PF32, SF, PBF, SG, ACC)                           \
  {                                                                             \
    ushort* sAc = sA + (CUR)*8192;                                              \
    ushort* sBc = sB + (CUR)*8192;                                              \
    bf16x8 af[2][4], bfr[2][4];                                                 \
    _Pragma("unroll")                                                           \
    for (int kk = 0; kk < 2; ++kk){                                             \
      int cb = kk*4 + (lane >> 4);                                              \
      _Pragma("unroll")                                                         \
      for (int x = 0; x < 4; ++x){                                              \
        int ra = wr*64 + x*16 + (lane & 15);                                    \
        af[kk][x]  = *(const bf16x8*)(sAc + ra*64 + ((cb ^ (ra & 7)) << 3));    \
        int rb = wc*64 + x*16 + (lane & 15);                                    \
        bfr[kk][x] = *(const bf16x8*)(sBc + rb*64 + ((cb ^ (rb & 7)) << 3));    \
      }                                                                         \
    }                                                                           \
    asm volatile("s_waitcnt lgkmcnt(0)" ::: "memory");                          \
    __builtin_amdgcn_sched_barrier(0);                                          \
    __builtin_amdgcn_s_barrier();                                               \
    if ((T) <= 13){                                                             \
      ISSUE_BF(PBF, ((T)+2)*64, (SG) + (CUR)*8192);                             \
      ISSUE_F32(PF32, ((T)+2)*64, RC);                                          \
      asm volatile("s_waitcnt vmcnt(12)" ::: "memory");                         \
    } else if ((T) == 14){                                                      \
      asm volatile("s_waitcnt vmcnt(0)" ::: "memory");                          \
    }                                                                           \
    if ((T) <= 14) DSW(RN, (SF) + (((CUR))^1)*8192);                            \
    __builtin_amdgcn_s_setprio(1);                                              \
    _Pragma("unroll")                                                           \
    for (int kk = 0; kk < 2; ++kk)                                              \
      _Pragma("unroll")                                                         \
      for (int x = 0; x < 4; ++x)                                               \
        _Pragma("unroll")                                                       \
        for (int y = 0; y < 4; ++y)                                             \
          ACC[x][y] = __builtin_amdgcn_mfma_f32_16x16x32_bf16(                  \
                          af[kk][x], bfr[kk][y], ACC[x][y], 0, 0, 0);           \
    __builtin_amdgcn_s_setprio(0);                                              \
    asm volatile("s_waitcnt lgkmcnt(0)" ::: "memory");                          \
    __builtin_amdgcn_s_barrier();                                               \
  }

// Full 1024-deep contraction: PF32 (f32 panel) staged via regs into SF;
// PBF (bf16 panel) via global_load_lds into SG. Depth-2 double buffer.
#define GEMM_CORE_MIX(PF32, SF, PBF, SG, R0, R1, ACC)                           \
  {                                                                             \
    ISSUE_BF(PBF, 0, SG);                                                       \
    ISSUE_F32(PF32, 0, R0);                                                     \
    ISSUE_BF(PBF, 64, (SG) + 8192);                                             \
    ISSUE_F32(PF32, 64, R1);                                                    \
    asm volatile("s_waitcnt vmcnt(12)" ::: "memory");                           \
    DSW(R0, SF);                                                                \
    asm volatile("s_waitcnt lgkmcnt(0)" ::: "memory");                          \
    __builtin_amdgcn_s_barrier();                                               \
    for (int tt = 0; tt < 8; ++tt){                                             \
      PHASE(0, R0, R1, tt*2,   PF32, SF, PBF, SG, ACC)                          \
      PHASE(1, R1, R0, tt*2+1, PF32, SF, PBF, SG, ACC)                          \
    }                                                                           \
  }

// ---------------- fused: hp-tile GEMM + P-tile GEMM + diag epilogue ----------------
__global__ __launch_bounds__(256, 2) void fused_diag(
    const float* __restrict__ h, const ushort* __restrict__ pwbf,
    const ushort* __restrict__ ubf, const float* __restrict__ lam,
    const float* __restrict__ pb, float* __restrict__ partial)
{
  __shared__ ushort sA[2*128*64];
  __shared__ ushort sB[2*128*64];
  int bid = xcd_swz((int)blockIdx.x, (int)gridDim.x);
  int bl = bid >> 6;                 // batch
  int t_ = bid & 63;
  int it = t_ >> 3, ft = t_ & 7;
  const float*  PanH = h    + ((size_t)bl << 20) + (size_t)(it*128) * D_;
  const ushort* PanW = pwbf + (size_t)(ft*128) * D_;
  const ushort* PanU = ubf  + (size_t)(it*128) * D_;
  const float*  PanL = lam  + ((size_t)bl << 20) + (size_t)(ft*128) * D_;
  int tid = threadIdx.x, lane = tid & 63, wv = tid >> 6;
  int wr = wv >> 1, wc = wv & 1;
  int srow = lane >> 3;
  int scol = (((lane & 7) ^ srow) << 3);   // bf16-side pre-swizzled source chunk
  int rrow = tid >> 3;                      // f32-side: row within 32-row group
  int rcol = (tid & 7) << 3;                // 8 consecutive floats
  int rsw  = (((tid & 7) ^ (rrow & 7)) << 3); // swizzled ushort offset in row

  f32x4 rS0[8], rS1[8];                     // f32 staging regs, depth-2

  f32x4 acc[4][4];
  #pragma unroll
  for (int x = 0; x < 4; ++x)
    #pragma unroll
    for (int y = 0; y < 4; ++y) acc[x][y] = (f32x4){0.f,0.f,0.f,0.f};

  // ---- loop 1: hp-tile = h @ pw^T  (h f32-staged -> sA; pw gload_lds -> sB) ----
  GEMM_CORE_MIX(PanH, sA, PanW, sB, rS0, rS1, acc)

  // pack hp (+pb) to bf16 in registers; reset acc for loop 2
  us4 hp_pk[4][4];
  #pragma unroll
  for (int y = 0; y < 4; ++y){
    int gk = ft*128 + wc*64 + y*16 + (lane & 15);
    float pbv = pb[gk];
    #pragma unroll
    for (int x = 0; x < 4; ++x){
      us4 p;
      p.x = f2bf(acc[x][y][0] + pbv); p.y = f2bf(acc[x][y][1] + pbv);
      p.z = f2bf(acc[x][y][2] + pbv); p.w = f2bf(acc[x][y][3] + pbv);
      hp_pk[x][y] = p;
      acc[x][y] = (f32x4){0.f,0.f,0.f,0.f};
    }
  }

  // ---- loop 2: P-tile = u @ lam^T  (lam f32-staged -> sB; u gload_lds -> sA) ----
  GEMM_CORE_MIX(PanL, sB, PanU, sA, rS0, rS1, acc)

  // ---- epilogue: ps = rowsum over this wave's 64 cols of hp .* P ----
  f32x4 ps[4];
  #pragma unroll
  for (int x = 0; x < 4; ++x) ps[x] = (f32x4){0.f,0.f,0.f,0.f};
  #pragma unroll
  for (int y = 0; y < 4; ++y)
    #pragma unroll
    for (int x = 0; x < 4; ++x){
      ps[x][0] += bf2f(hp_pk[x][y].x) * acc[x][y][0];
      ps[x][1] += bf2f(hp_pk[x][y].y) * acc[x][y][1];
      ps[x][2] += bf2f(hp_pk[x][y].z) * acc[x][y][2];
      ps[x][3] += bf2f(hp_pk[x][y].w) * acc[x][y][3];
    }
  // butterfly over the 16 cols (lane bits 0..3); preserves row group (lane>>4)
  #pragma unroll
  for (int x = 0; x < 4; ++x)
    #pragma unroll
    for (int r = 0; r < 4; ++r){
      float v = ps[x][r];
      #pragma unroll
      for (int mm = 1; mm < 16; mm <<= 1) v += __shfl_xor(v, mm, 64);
      ps[x][r] = v;
    }
  // deterministic partial strips: strip = ft*2 + wc  (16 strips)
  if ((lane & 15) == 0){
    int strip = ft*2 + wc;
    float* pdst = partial + (size_t)strip*(BATCH*D_) + (size_t)bl*D_;
    #pragma unroll
    for (int x = 0; x < 4; ++x){
      int gi0 = it*128 + wr*64 + x*16 + (lane >> 4)*4;
      #pragma unroll
      for (int r = 0; r < 4; ++r) pdst[gi0 + r] = ps[x][r];
    }
  }
}

// ---------------- K3: diag = sum(strips) + bias; broadcast to 96 ----------------
__global__ __launch_bounds__(128) void bcast_out(
    const float* __restrict__ partial, const float* __restrict__ bias,
    float* __restrict__ out)
{
  int row = blockIdx.x;             // b*1024 + i
  int i = row & (D_-1);
  float s = bias[i];
  #pragma unroll
  for (int st = 0; st < 16; ++st) s += partial[(size_t)st*(BATCH*D_) + row];
  if (threadIdx.x < PRED) out[(size_t)row*PRED + threadIdx.x] = s;
}

// ---------------- emergency path: no workspace needed (slow, correct) ----------------
__global__ __launch_bounds__(256) void emergency_fused(
    const float* __restrict__ h, const float* __restrict__ lam,
    const float* __restrict__ uu, const float* __restrict__ bias,
    const float* __restrict__ pw, const float* __restrict__ pb,
    float* __restrict__ out)
{
  int b = blockIdx.x >> 10;
  int i = blockIdx.x & (D_-1);
  __shared__ float hps[D_];
  __shared__ float red[4];
  __shared__ float dv;
  const float* hrow = h + ((size_t)b << 20) + (size_t)i*D_;
  for (int f = threadIdx.x; f < D_; f += 256){
    const float* pwr = pw + (size_t)f*D_;
    float s = pb[f];
    for (int c = 0; c < D_; ++c) s += hrow[c]*pwr[c];
    hps[f] = s;
  }
  __syncthreads();
  const float* urow = uu + (size_t)i*D_;
  float d = 0.f;
  for (int f = threadIdx.x; f < D_; f += 256){
    const float* lr = lam + ((size_t)b << 20) + (size_t)f*D_;
    float p = 0.f;
    for (int m = 0; m < D_; ++m) p += lr[m]*urow[m];
    d += hps[f]*p;
  }
  for (int off = 32; off; off >>= 1) d += __shfl_down(d, off, 64);
  if ((threadIdx.x & 63) == 0) red[threadIdx.x >> 6] = d;
  __syncthreads();
  if (threadIdx.x == 0) dv = red[0]+red[1]+red[2]+red[3] + bias[i];
  __syncthreads();
  if (threadIdx.x < PRED) out[(size_t)blockIdx.x*PRED + threadIdx.x] = dv;
}

extern "C" void kernel_launch(void* const* d_in, const int* in_sizes, int n_in,
                              void* d_out, int out_size, void* d_ws, size_t ws_size,
                              hipStream_t stream) {
  const float* h    = (const float*)d_in[0];
  const float* lam  = (const float*)d_in[1];
  const float* uu   = (const float*)d_in[2];
  const float* bias = (const float*)d_in[3];
  const float* pw   = (const float*)d_in[4];
  const float* pb   = (const float*)d_in[5];
  float* out = (float*)d_out;

  const size_t MB = 1ull << 20;

  if (ws_size >= 8*MB) {
    float*  partial = (float*)d_ws;                       // 4 MB
    ushort* u_bf    = (ushort*)((char*)d_ws + 4*MB);      // 2 MB
    ushort* pw_bf   = (ushort*)((char*)d_ws + 6*MB);      // 2 MB

    cvt_bf16<<<dim3(512), dim3(256), 0, stream>>>(uu, u_bf, 262144);
    cvt_bf16<<<dim3(512), dim3(256), 0, stream>>>(pw, pw_bf, 262144);
    fused_diag<<<dim3(BATCH*64), dim3(256), 0, stream>>>(h, pw_bf, u_bf, lam, pb, partial);
    bcast_out<<<dim3(BATCH*D_), dim3(128), 0, stream>>>(partial, bias, out);
  } else {
    emergency_fused<<<dim3(BATCH*D_), dim3(256), 0, stream>>>(h, lam, uu, bias, pw, pb, out);
  }
}

// Round 7
// 592.454 us; speedup vs baseline: 1.1245x; 1.1245x over previous
//
#include <hip/hip_runtime.h>
#include <hip/hip_bf16.h>

// B=64, D=1024, M=1024, DMODEL=1024, PRED_LEN=96
//   hp[b,i,f] = sum_c h[b,i,c]*pw[f,c] + pb[f]
//   P [b,i,f] = sum_m u[i,m]*lam[b,f,m]
//   diag[b,i] = sum_f hp[b,i,f]*P[b,i,f];  out[b,i,:] = diag[b,i] + bias[i]
//
// Pipeline: cvt(f32->bf16, copy-class 32B-in/16B-out per lane) -> ONE fused
// kernel per (b, i-tile, f-tile): hp-tile GEMM (c-loop) -> pack bf16+pb in
// regs -> P-tile GEMM (m-loop, same counted-vmcnt dbuf core) -> in-register
// hadamard/rowsum -> 16 partial strips -> strip-sum broadcast.

#define D_    1024
#define BATCH 64
#define PRED  96

typedef __attribute__((ext_vector_type(8))) short  bf16x8;
typedef __attribute__((ext_vector_type(8))) ushort ushort8;
typedef __attribute__((ext_vector_type(4))) float  f32x4;
typedef __attribute__((ext_vector_type(4))) ushort us4;

__device__ __forceinline__ ushort f2bf(float f){
  union { __hip_bfloat16 b; ushort u; } cv;
  cv.b = __float2bfloat16(f);
  return cv.u;
}
__device__ __forceinline__ float bf2f(ushort v){
  union { ushort u; __hip_bfloat16 b; } cv;
  cv.u = v;
  return __bfloat162float(cv.b);
}

// bijective XCD swizzle (m204 form)
__device__ __forceinline__ int xcd_swz(int orig, int nwg){
  int q = nwg >> 3, r = nwg & 7;
  int x = orig & 7, o = orig >> 3;
  return (x < r ? x*(q+1) : r*(q+1) + (x-r)*q) + o;
}

// async global->LDS, 16B per lane; LDS dest = wave-uniform base + lane*16
__device__ __forceinline__ void gload16(const ushort* g, ushort* l){
  __builtin_amdgcn_global_load_lds(
      (const __attribute__((address_space(1))) void*)g,
      (__attribute__((address_space(3))) void*)l, 16, 0, 0);
}

// ------- f32 -> bf16 convert: 2 float4 in / 1 ushort8 out per thread-iter -------
__global__ __launch_bounds__(256) void cvt_bf16(const float* __restrict__ in,
                                                ushort* __restrict__ out, int n8){
  int stride = (int)gridDim.x * 256;
  for (int i = (int)blockIdx.x*256 + (int)threadIdx.x; i < n8; i += stride){
    f32x4 a = *((const f32x4*)in + 2*(size_t)i);
    f32x4 b = *((const f32x4*)in + 2*(size_t)i + 1);
    ushort8 o;
    o[0]=f2bf(a.x); o[1]=f2bf(a.y); o[2]=f2bf(a.z); o[3]=f2bf(a.w);
    o[4]=f2bf(b.x); o[5]=f2bf(b.y); o[6]=f2bf(b.z); o[7]=f2bf(b.w);
    *(ushort8*)(out + (size_t)i*8) = o;
  }
}

// Shared K-loop core (depth-2 counted pipeline), proven R3/R5 (0 bank conflicts).
// LDS: sA/sB each 2 x 128x64 ushorts (dbuf).
// T2: LDS[r][chunk] = G[r][chunk ^ (r&7)] via pre-swizzled source; reads XOR back.
#define GEMM_CORE(Apan, Bpan, ACC)                                              \
  {                                                                             \
    _Pragma("unroll")                                                           \
    for (int q = 0; q < 4; ++q){                                                \
      int r0 = q*32 + wv*8;                                                     \
      gload16(Apan + (size_t)(r0 + srow)*D_ + scol, sA + r0*64);                \
      gload16(Bpan + (size_t)(r0 + srow)*D_ + scol, sB + r0*64);                \
    }                                                                           \
    _Pragma("unroll")                                                           \
    for (int q = 0; q < 4; ++q){                                                \
      int r0 = q*32 + wv*8;                                                     \
      gload16(Apan + 64 + (size_t)(r0 + srow)*D_ + scol, sA + 128*64 + r0*64);  \
      gload16(Bpan + 64 + (size_t)(r0 + srow)*D_ + scol, sB + 128*64 + r0*64);  \
    }                                                                           \
    for (int t = 0; t < 16; ++t){                                               \
      const int cur = t & 1;                                                    \
      ushort* sAc = sA + cur*(128*64);                                          \
      ushort* sBc = sB + cur*(128*64);                                          \
      if (t < 15) asm volatile("s_waitcnt vmcnt(8)" ::: "memory");              \
      else        asm volatile("s_waitcnt vmcnt(0)" ::: "memory");              \
      __builtin_amdgcn_s_barrier();                                             \
      bf16x8 af[2][4], bfr[2][4];                                               \
      _Pragma("unroll")                                                         \
      for (int kk = 0; kk < 2; ++kk){                                           \
        int cb = kk*4 + (lane >> 4);                                            \
        _Pragma("unroll")                                                       \
        for (int x = 0; x < 4; ++x){                                            \
          int ra = wr*64 + x*16 + (lane & 15);                                  \
          af[kk][x]  = *(const bf16x8*)(sAc + ra*64 + ((cb ^ (ra & 7)) << 3));  \
          int rb = wc*64 + x*16 + (lane & 15);                                  \
          bfr[kk][x] = *(const bf16x8*)(sBc + rb*64 + ((cb ^ (rb & 7)) << 3));  \
        }                                                                       \
      }                                                                         \
      asm volatile("s_waitcnt lgkmcnt(0)" ::: "memory");                        \
      __builtin_amdgcn_sched_barrier(0);                                        \
      __builtin_amdgcn_s_barrier();                                             \
      if (t < 14){                                                              \
        const ushort* An = Apan + (t+2)*64;                                     \
        const ushort* Bn = Bpan + (t+2)*64;                                     \
        _Pragma("unroll")                                                       \
        for (int q = 0; q < 4; ++q){                                            \
          int r0 = q*32 + wv*8;                                                 \
          gload16(An + (size_t)(r0 + srow)*D_ + scol, sAc + r0*64);             \
          gload16(Bn + (size_t)(r0 + srow)*D_ + scol, sBc + r0*64);             \
        }                                                                       \
      }                                                                         \
      __builtin_amdgcn_s_setprio(1);                                            \
      _Pragma("unroll")                                                         \
      for (int kk = 0; kk < 2; ++kk)                                            \
        _Pragma("unroll")                                                       \
        for (int x = 0; x < 4; ++x)                                             \
          _Pragma("unroll")                                                     \
          for (int y = 0; y < 4; ++y)                                           \
            ACC[x][y] = __builtin_amdgcn_mfma_f32_16x16x32_bf16(                \
                            af[kk][x], bfr[kk][y], ACC[x][y], 0, 0, 0);         \
      __builtin_amdgcn_s_setprio(0);                                            \
    }                                                                           \
  }

// ---------------- fused: hp-tile GEMM + P-tile GEMM + diag epilogue ----------------
__global__ __launch_bounds__(256, 2) void fused_diag(
    const ushort* __restrict__ hbf, const ushort* __restrict__ pwbf,
    const ushort* __restrict__ ubf, const ushort* __restrict__ lambf,
    const float* __restrict__ pb, float* __restrict__ partial, int b0)
{
  __shared__ ushort sA[2*128*64];
  __shared__ ushort sB[2*128*64];
  int bid = xcd_swz((int)blockIdx.x, (int)gridDim.x);
  int bl = bid >> 6;
  int t_ = bid & 63;
  int it = t_ >> 3, ft = t_ & 7;
  const ushort* ApanH = hbf  + ((size_t)bl << 20) + (size_t)(it*128) * D_;
  const ushort* BpanW = pwbf + (size_t)(ft*128) * D_;
  const ushort* ApanU = ubf  + (size_t)(it*128) * D_;
  const ushort* BpanL = lambf + ((size_t)bl << 20) + (size_t)(ft*128) * D_;
  int tid = threadIdx.x, lane = tid & 63, wv = tid >> 6;
  int wr = wv >> 1, wc = wv & 1;
  int srow = lane >> 3;
  int scol = (((lane & 7) ^ srow) << 3);     // T2 pre-swizzled source chunk

  f32x4 acc[4][4];
  #pragma unroll
  for (int x = 0; x < 4; ++x)
    #pragma unroll
    for (int y = 0; y < 4; ++y) acc[x][y] = (f32x4){0.f,0.f,0.f,0.f};

  // ---- loop 1: hp-tile = h @ pw^T ----
  GEMM_CORE(ApanH, BpanW, acc)

  // pack hp (+pb) to bf16 in registers; reset acc for loop 2
  us4 hp_pk[4][4];
  #pragma unroll
  for (int y = 0; y < 4; ++y){
    int gk = ft*128 + wc*64 + y*16 + (lane & 15);
    float pbv = pb[gk];
    #pragma unroll
    for (int x = 0; x < 4; ++x){
      us4 p;
      p.x = f2bf(acc[x][y][0] + pbv); p.y = f2bf(acc[x][y][1] + pbv);
      p.z = f2bf(acc[x][y][2] + pbv); p.w = f2bf(acc[x][y][3] + pbv);
      hp_pk[x][y] = p;
      acc[x][y] = (f32x4){0.f,0.f,0.f,0.f};
    }
  }

  // ---- loop 2: P-tile = u @ lam^T ----
  GEMM_CORE(ApanU, BpanL, acc)

  // ---- epilogue: ps = rowsum over this wave's 64 cols of hp .* P ----
  f32x4 ps[4];
  #pragma unroll
  for (int x = 0; x < 4; ++x) ps[x] = (f32x4){0.f,0.f,0.f,0.f};
  #pragma unroll
  for (int y = 0; y < 4; ++y)
    #pragma unroll
    for (int x = 0; x < 4; ++x){
      ps[x][0] += bf2f(hp_pk[x][y].x) * acc[x][y][0];
      ps[x][1] += bf2f(hp_pk[x][y].y) * acc[x][y][1];
      ps[x][2] += bf2f(hp_pk[x][y].z) * acc[x][y][2];
      ps[x][3] += bf2f(hp_pk[x][y].w) * acc[x][y][3];
    }
  // butterfly over the 16 cols (lane bits 0..3); preserves row group (lane>>4)
  #pragma unroll
  for (int x = 0; x < 4; ++x)
    #pragma unroll
    for (int r = 0; r < 4; ++r){
      float v = ps[x][r];
      #pragma unroll
      for (int mm = 1; mm < 16; mm <<= 1) v += __shfl_xor(v, mm, 64);
      ps[x][r] = v;
    }
  // deterministic partial strips: strip = ft*2 + wc  (16 strips)
  if ((lane & 15) == 0){
    int strip = ft*2 + wc;
    float* pdst = partial + (size_t)strip*(BATCH*D_) + (size_t)(b0 + bl)*D_;
    #pragma unroll
    for (int x = 0; x < 4; ++x){
      int gi0 = it*128 + wr*64 + x*16 + (lane >> 4)*4;
      #pragma unroll
      for (int r = 0; r < 4; ++r) pdst[gi0 + r] = ps[x][r];
    }
  }
}

// ---------------- K3: diag = sum(strips) + bias; broadcast to 96 ----------------
__global__ __launch_bounds__(128) void bcast_out(
    const float* __restrict__ partial, const float* __restrict__ bias,
    float* __restrict__ out)
{
  int row = blockIdx.x;             // b*1024 + i
  int i = row & (D_-1);
  float s = bias[i];
  #pragma unroll
  for (int st = 0; st < 16; ++st) s += partial[(size_t)st*(BATCH*D_) + row];
  if (threadIdx.x < PRED) out[(size_t)row*PRED + threadIdx.x] = s;
}

// ---------------- emergency path: no workspace needed (slow, correct) ----------------
__global__ __launch_bounds__(256) void emergency_fused(
    const float* __restrict__ h, const float* __restrict__ lam,
    const float* __restrict__ uu, const float* __restrict__ bias,
    const float* __restrict__ pw, const float* __restrict__ pb,
    float* __restrict__ out)
{
  int b = blockIdx.x >> 10;
  int i = blockIdx.x & (D_-1);
  __shared__ float hps[D_];
  __shared__ float red[4];
  __shared__ float dv;
  const float* hrow = h + ((size_t)b << 20) + (size_t)i*D_;
  for (int f = threadIdx.x; f < D_; f += 256){
    const float* pwr = pw + (size_t)f*D_;
    float s = pb[f];
    for (int c = 0; c < D_; ++c) s += hrow[c]*pwr[c];
    hps[f] = s;
  }
  __syncthreads();
  const float* urow = uu + (size_t)i*D_;
  float d = 0.f;
  for (int f = threadIdx.x; f < D_; f += 256){
    const float* lr = lam + ((size_t)b << 20) + (size_t)f*D_;
    float p = 0.f;
    for (int m = 0; m < D_; ++m) p += lr[m]*urow[m];
    d += hps[f]*p;
  }
  for (int off = 32; off; off >>= 1) d += __shfl_down(d, off, 64);
  if ((threadIdx.x & 63) == 0) red[threadIdx.x >> 6] = d;
  __syncthreads();
  if (threadIdx.x == 0) dv = red[0]+red[1]+red[2]+red[3] + bias[i];
  __syncthreads();
  if (threadIdx.x < PRED) out[(size_t)blockIdx.x*PRED + threadIdx.x] = dv;
}

extern "C" void kernel_launch(void* const* d_in, const int* in_sizes, int n_in,
                              void* d_out, int out_size, void* d_ws, size_t ws_size,
                              hipStream_t stream) {
  const float* h    = (const float*)d_in[0];
  const float* lam  = (const float*)d_in[1];
  const float* uu   = (const float*)d_in[2];
  const float* bias = (const float*)d_in[3];
  const float* pw   = (const float*)d_in[4];
  const float* pb   = (const float*)d_in[5];
  float* out = (float*)d_out;

  const size_t MB = 1ull << 20;
  const size_t FIXED = 4*MB /*partial*/ + 2*MB /*u_bf*/ + 2*MB /*pw_bf*/;

  if (ws_size >= FIXED + 4*MB) {
    float*  partial = (float*)d_ws;
    ushort* u_bf    = (ushort*)((char*)d_ws + 4*MB);
    ushort* pw_bf   = (ushort*)((char*)d_ws + 6*MB);
    char*   cbase   = (char*)d_ws + 8*MB;
    int cnb = (int)((ws_size - FIXED) / (4*MB));   // per-b: h_bf 2MB + lam_bf 2MB
    if (cnb > BATCH) cnb = BATCH;

    cvt_bf16<<<dim3(512),  dim3(256), 0, stream>>>(uu, u_bf, 131072);
    cvt_bf16<<<dim3(512),  dim3(256), 0, stream>>>(pw, pw_bf, 131072);

    for (int b0 = 0; b0 < BATCH; b0 += cnb){
      int nb = (BATCH - b0) < cnb ? (BATCH - b0) : cnb;
      ushort* h_bf   = (ushort*)cbase;
      ushort* lam_bf = (ushort*)(cbase + (size_t)nb*2*MB);
      cvt_bf16<<<dim3(4096), dim3(256), 0, stream>>>(h   + ((size_t)b0 << 20), h_bf,   nb*131072);
      cvt_bf16<<<dim3(4096), dim3(256), 0, stream>>>(lam + ((size_t)b0 << 20), lam_bf, nb*131072);
      fused_diag<<<dim3(nb*64), dim3(256), 0, stream>>>(h_bf, pw_bf, u_bf, lam_bf, pb, partial, b0);
    }
    bcast_out<<<dim3(BATCH*D_), dim3(128), 0, stream>>>(partial, bias, out);
  } else {
    emergency_fused<<<dim3(BATCH*D_), dim3(256), 0, stream>>>(h, lam, uu, bias, pw, pb, out);
  }
}

// Round 8
// 553.941 us; speedup vs baseline: 1.2027x; 1.0695x over previous
//
#include <hip/hip_runtime.h>
#include <hip/hip_bf16.h>

// B=64, D=1024, M=1024, DMODEL=1024, PRED_LEN=96
//   hp[b,i,f] = sum_c h[b,i,c]*pw[f,c] + pb[f]
//   P [b,i,f] = sum_m u[i,m]*lam[b,f,m]
//   diag[b,i] = sum_f hp[b,i,f]*P[b,i,f];  out[b,i,:] = diag[b,i] + bias[i]
//
// fused_diag reads h/lam DIRECTLY as f32 via global_load_lds (chunk-swizzled
// f32 LDS, dbuf 2x32KB, counted vmcnt(8) = two-phase latency budget) and
// pw/u as pre-converted bf16 (single-buffered 16KB LDS). f32->bf16 happens
// on the LDS->reg frag path (HW cvt). LDS total 80KB -> 2 blocks/CU.
// No big convert kernels.

#define D_    1024
#define BATCH 64
#define PRED  96

typedef __attribute__((ext_vector_type(8))) short  bf16x8;
typedef __attribute__((ext_vector_type(4))) float  f32x4;
typedef __attribute__((ext_vector_type(4))) ushort us4;

__device__ __forceinline__ ushort f2bf(float f){
  union { __hip_bfloat16 b; ushort u; } cv;
  cv.b = __float2bfloat16(f);
  return cv.u;
}
__device__ __forceinline__ float bf2f(ushort v){
  union { ushort u; __hip_bfloat16 b; } cv;
  cv.u = v;
  return __bfloat162float(cv.b);
}

// bijective XCD swizzle (m204 form)
__device__ __forceinline__ int xcd_swz(int orig, int nwg){
  int q = nwg >> 3, r = nwg & 7;
  int x = orig & 7, o = orig >> 3;
  return (x < r ? x*(q+1) : r*(q+1) + (x-r)*q) + o;
}

// async global->LDS, 16B per lane; LDS dest = wave-uniform base + lane*16
__device__ __forceinline__ void gload16(const ushort* g, ushort* l){
  __builtin_amdgcn_global_load_lds(
      (const __attribute__((address_space(1))) void*)g,
      (__attribute__((address_space(3))) void*)l, 16, 0, 0);
}
__device__ __forceinline__ void gload16f(const float* g, float* l){
  __builtin_amdgcn_global_load_lds(
      (const __attribute__((address_space(1))) void*)g,
      (__attribute__((address_space(3))) void*)l, 16, 0, 0);
}

// ------- f32 -> bf16 convert (tiny u/pw only) -------
__global__ __launch_bounds__(256) void cvt_bf16(const float* __restrict__ in,
                                                ushort* __restrict__ out, int n4){
  int stride = (int)gridDim.x * 256;
  for (int i = (int)blockIdx.x*256 + (int)threadIdx.x; i < n4; i += stride){
    f32x4 a = *((const f32x4*)in + i);
    us4 o;
    o.x = f2bf(a.x); o.y = f2bf(a.y); o.z = f2bf(a.z); o.w = f2bf(a.w);
    *(us4*)(out + (size_t)i*4) = o;
  }
}

// ---- staging: f32 tile 128x64, content chunk-swizzled:
//      LDS[row][c8*8+e] = G[row][(c8 ^ (row&7))*8 + e]   (c8: 8-f32 = 32B chunk)
// per wave: 8 issues x (64 lanes x 4 f32) = 4 rows/issue, linear LDS dest.
__device__ __forceinline__ void issue_f32(const float* pan, int toff, float* ldst,
                                          int wv, int frow, int fsw){
  #pragma unroll
  for (int q = 0; q < 8; ++q){
    gload16f(pan + toff + (size_t)(q*16 + frow)*D_ + fsw, ldst + (q*16 + wv*4)*64);
  }
}
// ---- staging: bf16 tile 128x64 (16B = 8-bf16 chunk swizzle), 4 issues/wave
__device__ __forceinline__ void issue_bf(const ushort* pan, int toff, ushort* ldst,
                                         int wv, int srow, int scol){
  #pragma unroll
  for (int q = 0; q < 4; ++q){
    int r0 = q*32 + wv*8;
    gload16(pan + toff + (size_t)(r0 + srow)*D_ + scol, ldst + r0*64);
  }
}

// ---- frag reads (XOR back the chunk swizzle) ----
__device__ __forceinline__ bf16x8 frag_bf(const ushort* sbuf, int r, int cb){
  return *(const bf16x8*)(sbuf + r*64 + ((cb ^ (r & 7)) << 3));
}
__device__ __forceinline__ bf16x8 frag_f32(const float* sbuf, int r, int cb){
  const float* p = sbuf + r*64 + ((cb ^ (r & 7)) << 3);
  f32x4 lo = *(const f32x4*)p;
  f32x4 hi = *(const f32x4*)(p + 4);
  bf16x8 f;
  f[0]=(short)f2bf(lo.x); f[1]=(short)f2bf(lo.y); f[2]=(short)f2bf(lo.z); f[3]=(short)f2bf(lo.w);
  f[4]=(short)f2bf(hi.x); f[5]=(short)f2bf(hi.y); f[6]=(short)f2bf(hi.z); f[7]=(short)f2bf(hi.w);
  return f;
}

// ---- one full 1024-deep contraction; F32A: which MFMA operand is the f32 side.
// vmcnt ledger (per phase, FIFO): issue B(t+1)[4] then F(t+2)[8]; at phase start
// outstanding = [F(t)8, B(t)4, F(t+1)8] -> vmcnt(8) drains F(t)+B(t).
template<int F32A>
__device__ __forceinline__ void gemm_loop(const float* PF, const ushort* PB,
    float* sF0, float* sF1, ushort* sG, f32x4 (&acc)[4][4],
    int wr, int wc, int lane, int wv, int frow, int fsw, int srow, int scol)
{
  issue_f32(PF, 0,  sF0, wv, frow, fsw);
  issue_bf (PB, 0,  sG,  wv, srow, scol);
  issue_f32(PF, 64, sF1, wv, frow, fsw);
  for (int t = 0; t < 16; ++t){
    float* sFc = (t & 1) ? sF1 : sF0;
    if (t < 15) asm volatile("s_waitcnt vmcnt(8)" ::: "memory");
    else        asm volatile("s_waitcnt vmcnt(0)" ::: "memory");
    __builtin_amdgcn_s_barrier();
    bf16x8 af[2][4], bfr[2][4];
    #pragma unroll
    for (int kk = 0; kk < 2; ++kk){
      int cb = kk*4 + (lane >> 4);
      #pragma unroll
      for (int x = 0; x < 4; ++x){
        int rr = x*16 + (lane & 15);
        if (F32A){
          af [kk][x] = frag_f32(sFc, wr*64 + rr, cb);
          bfr[kk][x] = frag_bf (sG,  wc*64 + rr, cb);
        } else {
          af [kk][x] = frag_bf (sG,  wr*64 + rr, cb);
          bfr[kk][x] = frag_f32(sFc, wc*64 + rr, cb);
        }
      }
    }
    asm volatile("s_waitcnt lgkmcnt(0)" ::: "memory");
    __builtin_amdgcn_sched_barrier(0);
    __builtin_amdgcn_s_barrier();
    if (t < 15) issue_bf (PB, (t+1)*64, sG,  wv, srow, scol);
    if (t < 14) issue_f32(PF, (t+2)*64, sFc, wv, frow, fsw);
    __builtin_amdgcn_s_setprio(1);
    #pragma unroll
    for (int kk = 0; kk < 2; ++kk)
      #pragma unroll
      for (int x = 0; x < 4; ++x)
        #pragma unroll
        for (int y = 0; y < 4; ++y)
          acc[x][y] = __builtin_amdgcn_mfma_f32_16x16x32_bf16(
                          af[kk][x], bfr[kk][y], acc[x][y], 0, 0, 0);
    __builtin_amdgcn_s_setprio(0);
  }
}

// ---------------- fused: hp-tile GEMM + P-tile GEMM + diag epilogue ----------------
__global__ __launch_bounds__(256, 2) void fused_diag(
    const float* __restrict__ h, const ushort* __restrict__ pwbf,
    const ushort* __restrict__ ubf, const float* __restrict__ lam,
    const float* __restrict__ pb, float* __restrict__ partial)
{
  __shared__ float  sF[2][128*64];   // 64 KB: f32 operand, double-buffered
  __shared__ ushort sG[128*64];      // 16 KB: bf16 operand, single-buffered
  int bid = xcd_swz((int)blockIdx.x, (int)gridDim.x);
  int bl = bid >> 6;                 // batch
  int t_ = bid & 63;
  int it = t_ >> 3, ft = t_ & 7;
  const float*  PanH = h    + ((size_t)bl << 20) + (size_t)(it*128) * D_;
  const ushort* PanW = pwbf + (size_t)(ft*128) * D_;
  const ushort* PanU = ubf  + (size_t)(it*128) * D_;
  const float*  PanL = lam  + ((size_t)bl << 20) + (size_t)(ft*128) * D_;
  int tid = threadIdx.x, lane = tid & 63, wv = tid >> 6;
  int wr = wv >> 1, wc = wv & 1;
  // bf16-side staging map (16B = 8-bf16 chunks)
  int srow = lane >> 3;
  int scol = (((lane & 7) ^ srow) << 3);
  // f32-side staging map (16B = 4-f32 half-chunks; 32B chunk swizzle)
  int frow = wv*4 + (lane >> 4);
  int fsw  = ((((lane & 15) >> 1) ^ (frow & 7)) << 3) + ((lane & 1) << 2);

  f32x4 acc[4][4];
  #pragma unroll
  for (int x = 0; x < 4; ++x)
    #pragma unroll
    for (int y = 0; y < 4; ++y) acc[x][y] = (f32x4){0.f,0.f,0.f,0.f};

  // ---- loop 1: hp-tile = h @ pw^T  (h = f32 A-side; pw = bf16 B-side) ----
  gemm_loop<1>(PanH, PanW, sF[0], sF[1], sG, acc, wr, wc, lane, wv, frow, fsw, srow, scol);

  // pack hp (+pb) to bf16 in registers; reset acc for loop 2
  us4 hp_pk[4][4];
  #pragma unroll
  for (int y = 0; y < 4; ++y){
    int gk = ft*128 + wc*64 + y*16 + (lane & 15);
    float pbv = pb[gk];
    #pragma unroll
    for (int x = 0; x < 4; ++x){
      us4 p;
      p.x = f2bf(acc[x][y][0] + pbv); p.y = f2bf(acc[x][y][1] + pbv);
      p.z = f2bf(acc[x][y][2] + pbv); p.w = f2bf(acc[x][y][3] + pbv);
      hp_pk[x][y] = p;
      acc[x][y] = (f32x4){0.f,0.f,0.f,0.f};
    }
  }

  // ---- loop 2: P-tile = u @ lam^T  (u = bf16 A-side; lam = f32 B-side) ----
  gemm_loop<0>(PanL, PanU, sF[0], sF[1], sG, acc, wr, wc, lane, wv, frow, fsw, srow, scol);

  // ---- epilogue: ps = rowsum over this wave's 64 cols of hp .* P ----
  f32x4 ps[4];
  #pragma unroll
  for (int x = 0; x < 4; ++x) ps[x] = (f32x4){0.f,0.f,0.f,0.f};
  #pragma unroll
  for (int y = 0; y < 4; ++y)
    #pragma unroll
    for (int x = 0; x < 4; ++x){
      ps[x][0] += bf2f(hp_pk[x][y].x) * acc[x][y][0];
      ps[x][1] += bf2f(hp_pk[x][y].y) * acc[x][y][1];
      ps[x][2] += bf2f(hp_pk[x][y].z) * acc[x][y][2];
      ps[x][3] += bf2f(hp_pk[x][y].w) * acc[x][y][3];
    }
  // butterfly over the 16 cols (lane bits 0..3); preserves row group (lane>>4)
  #pragma unroll
  for (int x = 0; x < 4; ++x)
    #pragma unroll
    for (int r = 0; r < 4; ++r){
      float v = ps[x][r];
      #pragma unroll
      for (int mm = 1; mm < 16; mm <<= 1) v += __shfl_xor(v, mm, 64);
      ps[x][r] = v;
    }
  // deterministic partial strips: strip = ft*2 + wc  (16 strips)
  if ((lane & 15) == 0){
    int strip = ft*2 + wc;
    float* pdst = partial + (size_t)strip*(BATCH*D_) + (size_t)bl*D_;
    #pragma unroll
    for (int x = 0; x < 4; ++x){
      int gi0 = it*128 + wr*64 + x*16 + (lane >> 4)*4;
      #pragma unroll
      for (int r = 0; r < 4; ++r) pdst[gi0 + r] = ps[x][r];
    }
  }
}

// ---------------- K3: diag = sum(strips) + bias; broadcast to 96 ----------------
__global__ __launch_bounds__(128) void bcast_out(
    const float* __restrict__ partial, const float* __restrict__ bias,
    float* __restrict__ out)
{
  int row = blockIdx.x;             // b*1024 + i
  int i = row & (D_-1);
  float s = bias[i];
  #pragma unroll
  for (int st = 0; st < 16; ++st) s += partial[(size_t)st*(BATCH*D_) + row];
  if (threadIdx.x < PRED) out[(size_t)row*PRED + threadIdx.x] = s;
}

// ---------------- emergency path: no workspace needed (slow, correct) ----------------
__global__ __launch_bounds__(256) void emergency_fused(
    const float* __restrict__ h, const float* __restrict__ lam,
    const float* __restrict__ uu, const float* __restrict__ bias,
    const float* __restrict__ pw, const float* __restrict__ pb,
    float* __restrict__ out)
{
  int b = blockIdx.x >> 10;
  int i = blockIdx.x & (D_-1);
  __shared__ float hps[D_];
  __shared__ float red[4];
  __shared__ float dv;
  const float* hrow = h + ((size_t)b << 20) + (size_t)i*D_;
  for (int f = threadIdx.x; f < D_; f += 256){
    const float* pwr = pw + (size_t)f*D_;
    float s = pb[f];
    for (int c = 0; c < D_; ++c) s += hrow[c]*pwr[c];
    hps[f] = s;
  }
  __syncthreads();
  const float* urow = uu + (size_t)i*D_;
  float d = 0.f;
  for (int f = threadIdx.x; f < D_; f += 256){
    const float* lr = lam + ((size_t)b << 20) + (size_t)f*D_;
    float p = 0.f;
    for (int m = 0; m < D_; ++m) p += lr[m]*urow[m];
    d += hps[f]*p;
  }
  for (int off = 32; off; off >>= 1) d += __shfl_down(d, off, 64);
  if ((threadIdx.x & 63) == 0) red[threadIdx.x >> 6] = d;
  __syncthreads();
  if (threadIdx.x == 0) dv = red[0]+red[1]+red[2]+red[3] + bias[i];
  __syncthreads();
  if (threadIdx.x < PRED) out[(size_t)blockIdx.x*PRED + threadIdx.x] = dv;
}

extern "C" void kernel_launch(void* const* d_in, const int* in_sizes, int n_in,
                              void* d_out, int out_size, void* d_ws, size_t ws_size,
                              hipStream_t stream) {
  const float* h    = (const float*)d_in[0];
  const float* lam  = (const float*)d_in[1];
  const float* uu   = (const float*)d_in[2];
  const float* bias = (const float*)d_in[3];
  const float* pw   = (const float*)d_in[4];
  const float* pb   = (const float*)d_in[5];
  float* out = (float*)d_out;

  const size_t MB = 1ull << 20;

  if (ws_size >= 8*MB) {
    float*  partial = (float*)d_ws;                       // 4 MB
    ushort* u_bf    = (ushort*)((char*)d_ws + 4*MB);      // 2 MB
    ushort* pw_bf   = (ushort*)((char*)d_ws + 6*MB);      // 2 MB

    cvt_bf16<<<dim3(512), dim3(256), 0, stream>>>(uu, u_bf, 262144);
    cvt_bf16<<<dim3(512), dim3(256), 0, stream>>>(pw, pw_bf, 262144);
    fused_diag<<<dim3(BATCH*64), dim3(256), 0, stream>>>(h, pw_bf, u_bf, lam, pb, partial);
    bcast_out<<<dim3(BATCH*D_), dim3(128), 0, stream>>>(partial, bias, out);
  } else {
    emergency_fused<<<dim3(BATCH*D_), dim3(256), 0, stream>>>(h, lam, uu, bias, pw, pb, out);
  }
}